// Round 1
// baseline (13832.765 us; speedup 1.0000x reference)
//
#include <hip/hip_runtime.h>
#include <stdint.h>
#include <math.h>

// Problem constants
#define NTOK 4096   // B*T
#define TSEQ 2048
#define CDIM 1024
#define NHEAD 16
#define DHEAD 64
#define NEXP 8
#define HIDN 4096
#define ECAP 1024

// ---------------- threefry2x32 (exact JAX semantics) ----------------
__device__ __forceinline__ void threefry2x32(uint32_t k0, uint32_t k1,
                                             uint32_t x0, uint32_t x1,
                                             uint32_t& o0, uint32_t& o1) {
  uint32_t ks2 = k0 ^ k1 ^ 0x1BD11BDAu;
#define TF_R(r) { x0 += x1; x1 = (x1 << (r)) | (x1 >> (32 - (r))); x1 ^= x0; }
  x0 += k0; x1 += k1;
  TF_R(13) TF_R(15) TF_R(26) TF_R(6)
  x0 += k1; x1 += ks2 + 1u;
  TF_R(17) TF_R(29) TF_R(16) TF_R(24)
  x0 += ks2; x1 += k0 + 2u;
  TF_R(13) TF_R(15) TF_R(26) TF_R(6)
  x0 += k0; x1 += k1 + 3u;
  TF_R(17) TF_R(29) TF_R(16) TF_R(24)
  x0 += k1; x1 += ks2 + 4u;
  TF_R(13) TF_R(15) TF_R(26) TF_R(6)
  x0 += ks2; x1 += k0 + 5u;
#undef TF_R
  o0 = x0; o1 = x1;
}

// XLA's f32 erf_inv (Giles 2012 polynomial, log1p variant)
__device__ __forceinline__ float erfinv_f32(float x) {
  float w = -log1pf(-x * x);
  float p;
  if (w < 5.0f) {
    w = w - 2.5f;
    p = 2.81022636e-08f;
    p = fmaf(p, w, 3.43273939e-07f);
    p = fmaf(p, w, -3.5233877e-06f);
    p = fmaf(p, w, -4.39150654e-06f);
    p = fmaf(p, w, 0.00021858087f);
    p = fmaf(p, w, -0.00125372503f);
    p = fmaf(p, w, -0.00417768164f);
    p = fmaf(p, w, 0.246640727f);
    p = fmaf(p, w, 1.50140941f);
  } else {
    w = sqrtf(w) - 3.0f;
    p = -0.000200214257f;
    p = fmaf(p, w, 0.000100950558f);
    p = fmaf(p, w, 0.00134934322f);
    p = fmaf(p, w, -0.00367342844f);
    p = fmaf(p, w, 0.00573950773f);
    p = fmaf(p, w, -0.0076224613f);
    p = fmaf(p, w, 0.00943887047f);
    p = fmaf(p, w, 1.00167406f);
    p = fmaf(p, w, 2.83297682f);
  }
  return p * x;
}

// ---------------- embedding ----------------
__global__ __launch_bounds__(256) void k_embed(const int* __restrict__ ids,
    const float* __restrict__ tok, const float* __restrict__ pos,
    float* __restrict__ x) {
  int row = blockIdx.x;
  int id = ids[row];
  int t = row & (TSEQ - 1);
  const float* tr = tok + (size_t)id * CDIM;
  const float* pr = pos + (size_t)t * CDIM;
  float* xr = x + (size_t)row * CDIM;
  for (int c = threadIdx.x; c < CDIM; c += 256) xr[c] = tr[c] + pr[c];
}

// ---------------- layernorm (two-pass, matches jnp.var) ----------------
__global__ __launch_bounds__(256) void k_ln(const float* __restrict__ in,
    float* __restrict__ out, const float* __restrict__ g, const float* __restrict__ b) {
  __shared__ float red[256];
  int row = blockIdx.x, tid = threadIdx.x;
  const float* xr = in + (size_t)row * CDIM;
  float s = 0.f;
  for (int c = tid; c < CDIM; c += 256) s += xr[c];
  red[tid] = s; __syncthreads();
  for (int off = 128; off > 0; off >>= 1) {
    if (tid < off) red[tid] += red[tid + off];
    __syncthreads();
  }
  float m = red[0] * (1.0f / CDIM);
  __syncthreads();
  float v = 0.f;
  for (int c = tid; c < CDIM; c += 256) { float d = xr[c] - m; v += d * d; }
  red[tid] = v; __syncthreads();
  for (int off = 128; off > 0; off >>= 1) {
    if (tid < off) red[tid] += red[tid + off];
    __syncthreads();
  }
  float var = red[0] * (1.0f / CDIM);
  float rstd = 1.0f / sqrtf(var + 1e-5f);
  float* orow = out + (size_t)row * CDIM;
  for (int c = tid; c < CDIM; c += 256)
    orow[c] = (xr[c] - m) * rstd * g[c] + b[c];
}

// ---------------- generic tiled fp32 GEMM ----------------
// C[M,N] (flags&2: +=) = act( A[gather?][K] @ B[K,N] + bias )
// flags&1: relu. countPtr: Meff = min(M, *countPtr) row limit (device-side).
__global__ __launch_bounds__(256) void k_gemm(
    const float* __restrict__ A, int lda,
    const float* __restrict__ B, int ldb,
    float* __restrict__ Cm, int ldc,
    int M, int N, int K,
    const float* __restrict__ bias,
    const int* __restrict__ gather,
    const int* __restrict__ countPtr,
    int flags) {
  __shared__ float As[16][68];  // pad 68: 16B-aligned rows, conflict-free
  __shared__ float Bs[16][64];
  const int tid = threadIdx.x;
  const int tx = tid & 15, ty = tid >> 4;
  const int row0 = blockIdx.y << 6, col0 = blockIdx.x << 6;
  int Meff = M;
  if (countPtr) { int cc = *countPtr; if (cc < Meff) Meff = cc; }
  if (row0 >= Meff) return;
  float acc[4][4];
#pragma unroll
  for (int i = 0; i < 4; i++)
#pragma unroll
    for (int j = 0; j < 4; j++) acc[i][j] = 0.f;
  const int a_m = tid >> 4, a_k = tid & 15;
  const int b_k = tid >> 6, b_n = tid & 63;
  for (int k0 = 0; k0 < K; k0 += 16) {
#pragma unroll
    for (int i = 0; i < 4; i++) {
      int m = a_m + (i << 4);
      int grow = row0 + m;
      float v = 0.f;
      if (grow < Meff) {
        int rsrc = gather ? gather[grow] : grow;
        v = A[(size_t)rsrc * lda + k0 + a_k];
      }
      As[a_k][m] = v;
    }
#pragma unroll
    for (int i = 0; i < 4; i++) {
      int kk = b_k + (i << 2);
      Bs[kk][b_n] = B[(size_t)(k0 + kk) * ldb + col0 + b_n];
    }
    __syncthreads();
#pragma unroll
    for (int kk = 0; kk < 16; kk++) {
      float a0 = As[kk][(ty << 2) + 0], a1 = As[kk][(ty << 2) + 1],
            a2 = As[kk][(ty << 2) + 2], a3 = As[kk][(ty << 2) + 3];
      float b0 = Bs[kk][(tx << 2) + 0], b1 = Bs[kk][(tx << 2) + 1],
            b2 = Bs[kk][(tx << 2) + 2], b3 = Bs[kk][(tx << 2) + 3];
      acc[0][0] += a0 * b0; acc[0][1] += a0 * b1; acc[0][2] += a0 * b2; acc[0][3] += a0 * b3;
      acc[1][0] += a1 * b0; acc[1][1] += a1 * b1; acc[1][2] += a1 * b2; acc[1][3] += a1 * b3;
      acc[2][0] += a2 * b0; acc[2][1] += a2 * b1; acc[2][2] += a2 * b2; acc[2][3] += a2 * b3;
      acc[3][0] += a3 * b0; acc[3][1] += a3 * b1; acc[3][2] += a3 * b2; acc[3][3] += a3 * b3;
    }
    __syncthreads();
  }
#pragma unroll
  for (int i = 0; i < 4; i++) {
    int grow = row0 + (ty << 2) + i;
    if (grow >= Meff) continue;
    float* crow = Cm + (size_t)grow * ldc + col0 + (tx << 2);
#pragma unroll
    for (int j = 0; j < 4; j++) {
      float v = acc[i][j];
      if (bias) v += bias[col0 + (tx << 2) + j];
      if (flags & 1) v = fmaxf(v, 0.f);
      if (flags & 2) v += crow[j];
      crow[j] = v;
    }
  }
}

// ---------------- attention: flash-style, fp32, no mask ----------------
// block = (t-tile of 32 rows) x head x batch; online softmax over s-tiles of 64
__global__ __launch_bounds__(256) void k_attn(const float* __restrict__ qkv,
                                              float* __restrict__ o) {
  const int t0 = blockIdx.x * 32;
  const int h = blockIdx.y;
  const int b = blockIdx.z;
  __shared__ float Qs[32][64];
  __shared__ float Ks[64][65];
  __shared__ float Vs[64][65];
  __shared__ float Ss[32][65];
  __shared__ float Ms[32], Ls[32];
  const int tid = threadIdx.x;
  for (int idx = tid; idx < 32 * 16; idx += 256) {
    int r = idx >> 4, d4 = (idx & 15) << 2;
    const float* src = qkv + ((size_t)(b * TSEQ + t0 + r) * 3 + 0) * CDIM + h * DHEAD + d4;
    float4 q = *(const float4*)src;
    Qs[r][d4 + 0] = q.x * 0.125f; Qs[r][d4 + 1] = q.y * 0.125f;  // /sqrt(64) exact
    Qs[r][d4 + 2] = q.z * 0.125f; Qs[r][d4 + 3] = q.w * 0.125f;
  }
  if (tid < 32) { Ms[tid] = -INFINITY; Ls[tid] = 0.f; }
  float Oa[8] = {0, 0, 0, 0, 0, 0, 0, 0};
  const int r = tid >> 3;   // row owned by this thread (8 threads/row, same wave)
  const int dl = tid & 7;
  __syncthreads();
  for (int s0 = 0; s0 < TSEQ; s0 += 64) {
    for (int idx = tid; idx < 64 * 16; idx += 256) {
      int j = idx >> 4, d4 = (idx & 15) << 2;
      const float* kp = qkv + ((size_t)(b * TSEQ + s0 + j) * 3 + 1) * CDIM + h * DHEAD + d4;
      float4 kk = *(const float4*)kp;
      Ks[j][d4 + 0] = kk.x; Ks[j][d4 + 1] = kk.y; Ks[j][d4 + 2] = kk.z; Ks[j][d4 + 3] = kk.w;
      const float* vp = qkv + ((size_t)(b * TSEQ + s0 + j) * 3 + 2) * CDIM + h * DHEAD + d4;
      float4 vv = *(const float4*)vp;
      Vs[j][d4 + 0] = vv.x; Vs[j][d4 + 1] = vv.y; Vs[j][d4 + 2] = vv.z; Vs[j][d4 + 3] = vv.w;
    }
    __syncthreads();
    {  // scores S = (Q/8) @ K^T
      const int j = tid & 63;
      const int r4 = tid >> 6;
#pragma unroll
      for (int i = 0; i < 8; i++) {
        int rr = r4 + (i << 2);
        float acc = 0.f;
#pragma unroll
        for (int d = 0; d < 64; d++) acc += Qs[rr][d] * Ks[j][d];
        Ss[rr][j] = acc;
      }
    }
    __syncthreads();
    // online softmax update (8 threads per row, within one wave)
    float mloc = -INFINITY;
#pragma unroll
    for (int i = 0; i < 8; i++) mloc = fmaxf(mloc, Ss[r][dl + (i << 3)]);
#pragma unroll
    for (int off = 4; off > 0; off >>= 1) mloc = fmaxf(mloc, __shfl_xor(mloc, off, 8));
    float mold = Ms[r];
    float mnew = fmaxf(mold, mloc);
    float alpha = expf(mold - mnew);
    float psum = 0.f;
#pragma unroll
    for (int i = 0; i < 8; i++) {
      int j = dl + (i << 3);
      float p = expf(Ss[r][j] - mnew);
      Ss[r][j] = p;
      psum += p;
    }
#pragma unroll
    for (int off = 4; off > 0; off >>= 1) psum += __shfl_xor(psum, off, 8);
    if (dl == 0) { Ms[r] = mnew; Ls[r] = Ls[r] * alpha + psum; }
#pragma unroll
    for (int i = 0; i < 8; i++) Oa[i] *= alpha;
    for (int j = 0; j < 64; j++) {
      float p = Ss[r][j];
#pragma unroll
      for (int i = 0; i < 8; i++) Oa[i] += p * Vs[j][(dl << 3) + i];
    }
    __syncthreads();
  }
  float linv = 1.0f / Ls[r];
  float* op = o + (size_t)(b * TSEQ + t0 + r) * CDIM + h * DHEAD + (dl << 3);
#pragma unroll
  for (int i = 0; i < 8; i++) op[i] = Oa[i] * linv;
}

// ---------------- router: logits + threefry noise + top-2 ----------------
__global__ __launch_bounds__(256) void k_route(
    const float* __restrict__ xn,
    const float* __restrict__ rw, const float* __restrict__ rb,
    const float* __restrict__ nw, const float* __restrict__ nb,
    int layer, int* __restrict__ topi, float* __restrict__ gate) {
  int token = blockIdx.x, tid = threadIdx.x;
  float acc[16];
#pragma unroll
  for (int j = 0; j < 16; j++) acc[j] = 0.f;
  const float* xr = xn + (size_t)token * CDIM;
  for (int c = tid; c < CDIM; c += 256) {
    float xc = xr[c];
    const float* w1p = rw + (size_t)c * NEXP;
    const float* w2p = nw + (size_t)c * NEXP;
#pragma unroll
    for (int j = 0; j < 8; j++) acc[j] += xc * w1p[j];
#pragma unroll
    for (int j = 0; j < 8; j++) acc[8 + j] += xc * w2p[j];
  }
#pragma unroll
  for (int j = 0; j < 16; j++) {
#pragma unroll
    for (int off = 32; off > 0; off >>= 1) acc[j] += __shfl_xor(acc[j], off, 64);
  }
  __shared__ float wp[4][16];
  int wid = tid >> 6;
  if ((tid & 63) == 0) {
#pragma unroll
    for (int j = 0; j < 16; j++) wp[wid][j] = acc[j];
  }
  __syncthreads();
  __shared__ float noisy[8];
  if (tid < 8) {
    int j = tid;
    float logit = wp[0][j] + wp[1][j] + wp[2][j] + wp[3][j] + rb[j];
    float nl = wp[0][8 + j] + wp[1][8 + j] + wp[2][8 + j] + wp[3][8 + j] + nb[j];
    float sp = fmaxf(nl, 0.f) + log1pf(expf(-fabsf(nl)));  // softplus
    // key_l = fold_in(key(42), layer) = threefry((0,42),(0,layer))
    uint32_t k0, k1, o0, o1;
    threefry2x32(0u, 42u, 0u, (uint32_t)layer, k0, k1);
    // partitionable random_bits: counter = (0, i), bits = o0 ^ o1
    uint32_t idx = (uint32_t)(token * NEXP + j);
    threefry2x32(k0, k1, 0u, idx, o0, o1);
    uint32_t bits = o0 ^ o1;
    float f = __uint_as_float((bits >> 9) | 0x3f800000u) - 1.0f;  // [0,1)
    const float lo = -0.99999994f;  // nextafter(-1,0); (hi-lo) rounds to 2.0f
    float u = fmaxf(lo, f * 2.0f + lo);
    float z = 1.41421356f * erfinv_f32(u);
    noisy[j] = logit + z * sp;
  }
  __syncthreads();
  if (tid == 0) {
    float v1 = -INFINITY; int i1 = 0;
#pragma unroll
    for (int j = 0; j < 8; j++) { float v = noisy[j]; if (v > v1) { v1 = v; i1 = j; } }
    float v2 = -INFINITY; int i2 = 0;
#pragma unroll
    for (int j = 0; j < 8; j++) {
      if (j == i1) continue;
      float v = noisy[j]; if (v > v2) { v2 = v; i2 = j; }
    }
    float e2 = expf(v2 - v1);
    float denom = 1.0f + e2;
    topi[token * 2] = i1; topi[token * 2 + 1] = i2;
    gate[token * 2] = 1.0f / denom;
    gate[token * 2 + 1] = e2 / denom;
  }
}

// ---------------- per-expert capacity scan (stable token order) ----------------
__global__ __launch_bounds__(256) void k_scan(const int* __restrict__ topi,
    int* __restrict__ perm, int* __restrict__ slot, int* __restrict__ count) {
  int e = blockIdx.x, tid = threadIdx.x;
  __shared__ int ps[256];
  __shared__ int sbase;
  if (tid == 0) sbase = 0;
  __syncthreads();
  for (int c0 = 0; c0 < NTOK; c0 += 256) {
    int token = c0 + tid;
    int j0 = topi[token * 2], j1 = topi[token * 2 + 1];
    int flag = (j0 == e || j1 == e) ? 1 : 0;
    ps[tid] = flag;
    __syncthreads();
    for (int off = 1; off < 256; off <<= 1) {
      int v = (tid >= off) ? ps[tid - off] : 0;
      __syncthreads();
      ps[tid] += v;
      __syncthreads();
    }
    int pos = sbase + ps[tid] - flag;  // exclusive prefix
    if (flag) {
      int s = (pos < ECAP) ? pos : -1;
      if (s >= 0) perm[e * ECAP + s] = token;
      if (j0 == e) slot[token * 2] = s;
      else slot[token * 2 + 1] = s;
    }
    __syncthreads();
    if (tid == 0) sbase += ps[255];
    __syncthreads();
  }
  if (tid == 0) count[e] = (sbase < ECAP) ? sbase : ECAP;
}

// ---------------- token-side gather of expert outputs, add into x ----------------
__global__ __launch_bounds__(256) void k_moe_add(
    const float* __restrict__ ybuf,
    const int* __restrict__ topi, const int* __restrict__ slot,
    const float* __restrict__ gate, float* __restrict__ x) {
  int token = blockIdx.x, tid = threadIdx.x;
  int e0 = topi[token * 2], s0 = slot[token * 2];
  int e1 = topi[token * 2 + 1], s1 = slot[token * 2 + 1];
  float g0 = gate[token * 2], g1 = gate[token * 2 + 1];
  const float* y0 = ybuf + ((size_t)e0 * ECAP + (s0 < 0 ? 0 : s0)) * CDIM;
  const float* y1 = ybuf + ((size_t)e1 * ECAP + (s1 < 0 ? 0 : s1)) * CDIM;
  float* xr = x + (size_t)token * CDIM;
  for (int c = tid; c < CDIM; c += 256) {
    float v = xr[c];
    if (s0 >= 0) v += g0 * y0[c];
    if (s1 >= 0) v += g1 * y1[c];
    xr[c] = v;
  }
}

// ---------------- head: out = xn @ head_w + head_b ----------------
__global__ __launch_bounds__(256) void k_head(const float* __restrict__ xn,
    const float* __restrict__ hw, const float* __restrict__ hb,
    float* __restrict__ out) {
  __shared__ float red[256];
  int token = blockIdx.x, tid = threadIdx.x;
  const float* xr = xn + (size_t)token * CDIM;
  float s = 0.f;
  for (int c = tid; c < CDIM; c += 256) s += xr[c] * hw[c];
  red[tid] = s; __syncthreads();
  for (int off = 128; off > 0; off >>= 1) {
    if (tid < off) red[tid] += red[tid + off];
    __syncthreads();
  }
  if (tid == 0) out[token] = red[0] + hb[0];
}

extern "C" void kernel_launch(void* const* d_in, const int* in_sizes, int n_in,
                              void* d_out, int out_size, void* d_ws, size_t ws_size,
                              hipStream_t stream) {
  const int* ids = (const int*)d_in[0];
  const float* tok_emb = (const float*)d_in[1];
  const float* pos_emb = (const float*)d_in[2];
  const float* ln1_g = (const float*)d_in[3];
  const float* ln1_b = (const float*)d_in[4];
  const float* ln2_g = (const float*)d_in[5];
  const float* ln2_b = (const float*)d_in[6];
  const float* qkv_w = (const float*)d_in[7];
  const float* out_w = (const float*)d_in[8];
  const float* route_w = (const float*)d_in[9];
  const float* route_b = (const float*)d_in[10];
  const float* noise_w = (const float*)d_in[11];
  const float* noise_b = (const float*)d_in[12];
  const float* w1 = (const float*)d_in[13];
  const float* b1 = (const float*)d_in[14];
  const float* w2 = (const float*)d_in[15];
  const float* b2 = (const float*)d_in[16];
  const float* lnf_g = (const float*)d_in[17];
  const float* lnf_b = (const float*)d_in[18];
  const float* head_w = (const float*)d_in[19];
  const float* head_b = (const float*)d_in[20];
  float* out = (float*)d_out;

  const size_t MB = 1024u * 1024u;
  char* ws = (char*)d_ws;
  float* x    = (float*)(ws);              // 16MB: residual stream
  float* xn   = (float*)(ws + 16 * MB);    // 16MB: LN out / attn out (o)
  float* qkv  = (float*)(ws + 32 * MB);    // 48MB
  float* hbuf = (float*)(ws + 32 * MB);    // 16MB (aliases qkv; used after attention)
  float* ybuf = (float*)(ws + 48 * MB);    // 32MB (aliases qkv; used after attention)
  char* small = ws + 80 * MB;
  int* topi = (int*)small;                 // 8192
  int* slot = topi + 2 * NTOK;             // 8192
  float* gate = (float*)(slot + 2 * NTOK); // 8192
  int* perm = (int*)(gate + 2 * NTOK);     // 8192
  int* count = perm + NEXP * ECAP;         // 8

  k_embed<<<NTOK, 256, 0, stream>>>(ids, tok_emb, pos_emb, x);

  for (int l = 0; l < 2; l++) {
    k_ln<<<NTOK, 256, 0, stream>>>(x, xn, ln1_g + l * CDIM, ln1_b + l * CDIM);
    // qkv = xn @ qkv_w[l]   (4096 x 3072 x 1024)
    k_gemm<<<dim3(48, 64), 256, 0, stream>>>(xn, CDIM,
        qkv_w + (size_t)l * CDIM * 3 * CDIM, 3 * CDIM, qkv, 3 * CDIM,
        NTOK, 3 * CDIM, CDIM, nullptr, nullptr, nullptr, 0);
    // attention -> o (into xn region)
    k_attn<<<dim3(TSEQ / 32, NHEAD, 2), 256, 0, stream>>>(qkv, xn);
    // x += o @ out_w[l]
    k_gemm<<<dim3(16, 64), 256, 0, stream>>>(xn, CDIM,
        out_w + (size_t)l * CDIM * CDIM, CDIM, x, CDIM,
        NTOK, CDIM, CDIM, nullptr, nullptr, nullptr, 2);
    // ln2 -> xn
    k_ln<<<NTOK, 256, 0, stream>>>(x, xn, ln2_g + l * CDIM, ln2_b + l * CDIM);
    // router
    k_route<<<NTOK, 256, 0, stream>>>(xn,
        route_w + (size_t)l * CDIM * NEXP, route_b + l * NEXP,
        noise_w + (size_t)l * CDIM * NEXP, noise_b + l * NEXP,
        l, topi, gate);
    k_scan<<<NEXP, 256, 0, stream>>>(topi, perm, slot, count);
    // expert FFNs (sequential; hbuf reused)
    for (int e = 0; e < NEXP; e++) {
      const size_t we = (size_t)(l * NEXP + e);
      // h = relu(xn[perm] @ w1 + b1)   (cap x 4096 x 1024)
      k_gemm<<<dim3(64, 16), 256, 0, stream>>>(xn, CDIM,
          w1 + we * CDIM * HIDN, HIDN, hbuf, HIDN,
          ECAP, HIDN, CDIM, b1 + we * HIDN, perm + e * ECAP, count + e, 1);
      // y = h @ w2 + b2                (cap x 1024 x 4096)
      k_gemm<<<dim3(16, 16), 256, 0, stream>>>(hbuf, HIDN,
          w2 + we * HIDN * CDIM, CDIM, ybuf + (size_t)e * ECAP * CDIM, CDIM,
          ECAP, CDIM, HIDN, b2 + we * CDIM, nullptr, count + e, 0);
    }
    k_moe_add<<<NTOK, 256, 0, stream>>>(ybuf, topi, slot, gate, x);
  }

  k_ln<<<NTOK, 256, 0, stream>>>(x, xn, lnf_g, lnf_b);
  k_head<<<NTOK, 256, 0, stream>>>(xn, head_w, head_b, out);
}